// Round 2
// baseline (446.128 us; speedup 1.0000x reference)
//
#include <hip/hip_runtime.h>
#include <math.h>

#define DIMC 512
#define VDIM 256
#define NVARS 320
#define NTOK 32768
#define NELEM (NTOK*DIMC)       // 16777216
#define IDX_OFF NELEM
#define PPL_OFF (NELEM + NTOK*2)
#define KM_OFF (PPL_OFF + 1)

// ws layout: doubles first: dsum[32] (double idx 0..32), dssq[32] (double idx 32..64)
//   == float offsets [0..128). Then float area:
#define OFF_MU   128   // 32 f32
#define OFF_RSTD 160   // 32 f32
#define OFF_LOSS 192   // 1 f32
#define OFF_ESQ  256   // 640 f32 -> [256,896)
#define OFF_HIST 1024  // 640 i32 -> [1024,1664)
#define WS_ZERO_FLOATS 1664

__global__ void k_init(float* ws) {
    int i = blockIdx.x * 256 + threadIdx.x;
    if (i < WS_ZERO_FLOATS) ws[i] = 0.0f;   // zero doubles too (bit pattern 0)
}

// e_sq[v*2+g] = sum_d emb[v][g][d]^2, fp64 accumulate -> correctly-rounded f32
__global__ void k_esq(const float* __restrict__ emb, float* ws) {
    int wave = blockIdx.x * 4 + (threadIdx.x >> 6);
    int lane = threadIdx.x & 63;
    const float* p = emb + (size_t)wave * VDIM;
    double s = 0.0;
    for (int j = lane; j < VDIM; j += 64) { double v = (double)p[j]; s += v * v; }
    for (int off = 32; off; off >>= 1) s += __shfl_down(s, off);
    if (lane == 0) ws[OFF_ESQ + wave] = (float)s;
}

// y = x @ W^T per group (tile 128 tok x 64 o, K=256 in 64-chunks), fused GN stats (fp64)
__global__ __launch_bounds__(256) void k_gemm(const float* __restrict__ x,
                                              const float* __restrict__ w,
                                              float* __restrict__ y, float* ws) {
    __shared__ float As[64][132];   // [k][tok], padded
    __shared__ float Ws[64][68];    // [k][o]
    __shared__ double red1[256];
    __shared__ double red2[256];
    const int tid = threadIdx.x;
    const int ty = tid >> 4, tx = tid & 15;
    const int tok0 = blockIdx.x * 128;
    const int o0 = blockIdx.y * 64;
    const int g = blockIdx.z;
    const int b = tok0 >> 11;
    const int kq = tid & 15;
    const int tb = tid >> 4;

    float acc[8][4];
#pragma unroll
    for (int i = 0; i < 8; i++)
#pragma unroll
        for (int j = 0; j < 4; j++) acc[i][j] = 0.0f;

    for (int k0 = 0; k0 < 256; k0 += 64) {
        __syncthreads();
#pragma unroll
        for (int it = 0; it < 8; it++) {
            int tok = tb + 16 * it;
            float4 v = *(const float4*)(x + (size_t)(tok0 + tok) * DIMC + g * VDIM + k0 + kq * 4);
            As[kq * 4 + 0][tok] = v.x; As[kq * 4 + 1][tok] = v.y;
            As[kq * 4 + 2][tok] = v.z; As[kq * 4 + 3][tok] = v.w;
        }
#pragma unroll
        for (int it = 0; it < 4; it++) {
            int o = tb + 16 * it;
            float4 v = *(const float4*)(w + (size_t)(g * 256 + o0 + o) * 256 + k0 + kq * 4);
            Ws[kq * 4 + 0][o] = v.x; Ws[kq * 4 + 1][o] = v.y;
            Ws[kq * 4 + 2][o] = v.z; Ws[kq * 4 + 3][o] = v.w;
        }
        __syncthreads();
#pragma unroll 8
        for (int k = 0; k < 64; k++) {
            const float4 a0 = *(const float4*)&As[k][ty * 8];
            const float4 a1 = *(const float4*)&As[k][ty * 8 + 4];
            const float4 e4 = *(const float4*)&Ws[k][tx * 4];
            float av[8] = {a0.x, a0.y, a0.z, a0.w, a1.x, a1.y, a1.z, a1.w};
            float ev[4] = {e4.x, e4.y, e4.z, e4.w};
#pragma unroll
            for (int i = 0; i < 8; i++)
#pragma unroll
                for (int j = 0; j < 4; j++) acc[i][j] = fmaf(av[i], ev[j], acc[i][j]);
        }
    }
    // epilogue: store y + per-(b,g) sum/sumsq in fp64
    double s1 = 0.0, s2 = 0.0;
#pragma unroll
    for (int i = 0; i < 8; i++) {
        int tok = tok0 + ty * 8 + i;
        float4 v = make_float4(acc[i][0], acc[i][1], acc[i][2], acc[i][3]);
        *(float4*)(y + (size_t)tok * DIMC + g * VDIM + o0 + tx * 4) = v;
        s1 += (double)v.x + (double)v.y + (double)v.z + (double)v.w;
        s2 += (double)v.x * v.x + (double)v.y * v.y + (double)v.z * v.z + (double)v.w * v.w;
    }
    red1[tid] = s1; red2[tid] = s2;
    __syncthreads();
    for (int s = 128; s; s >>= 1) {
        if (tid < s) { red1[tid] += red1[tid + s]; red2[tid] += red2[tid + s]; }
        __syncthreads();
    }
    if (tid == 0) {
        double* dws = (double*)ws;
        atomicAdd(&dws[b * 2 + g], red1[0]);
        atomicAdd(&dws[32 + b * 2 + g], red2[0]);
    }
}

__global__ void k_stats(float* ws) {
    int i = threadIdx.x;
    if (i < 32) {
        const double* d = (const double*)ws;
        double mu = d[i] * (1.0 / 524288.0);
        double var = d[32 + i] * (1.0 / 524288.0) - mu * mu;
        float varf = (float)var;
        ws[OFF_MU + i] = (float)mu;
        ws[OFF_RSTD + i] = 1.0f / sqrtf(varf + 1e-5f);   // correctly-rounded, matches 1/np.sqrt
    }
}

// normalize + VQ argmin over fp32-quantized d2 = (z_sq - 2*dot) + e_sq (mimics reference
// rounding so quantization-ties resolve to lowest index exactly like np.argmin)
__global__ __launch_bounds__(256) void k_vq(const float* __restrict__ emb,
                                            const float* __restrict__ gnw,
                                            const float* __restrict__ gnb,
                                            float* out, float* ws) {
    __shared__ float As[64][132];   // [k][tok] = ze
    __shared__ float Es[64][68];    // [k][v]
    __shared__ double zpartd[2048]; // 16KB; later aliased as red_r/red_v
    __shared__ float zsq[128];
    __shared__ float dl[128];
    __shared__ int   idxs[128];
    float* red_r = (float*)zpartd;          // bytes [0,8192)
    int*   red_v = (int*)(zpartd + 1024);   // bytes [8192,16384)

    const int tid = threadIdx.x;
    const int ty = tid >> 4, tx = tid & 15;
    const int tok0 = blockIdx.x * 128;
    const int g = blockIdx.y;
    const int b = tok0 >> 11;
    const int kq = tid & 15;
    const int tb = tid >> 4;
    const float mu = ws[OFF_MU + b * 2 + g];
    const float rstd = ws[OFF_RSTD + b * 2 + g];
    int* hist = ((int*)ws) + OFF_HIST;
    const float* y = out;

    float best_r[8]; int best_v[8];
    float zs[8];
    double zacc[8];
#pragma unroll
    for (int i = 0; i < 8; i++) { best_r[i] = 3.0e38f; best_v[i] = 0; zs[i] = 0.0f; zacc[i] = 0.0; }

    for (int vt = 0; vt < 5; vt++) {
        const int v0 = vt * 64;
        float acc[8][4];
#pragma unroll
        for (int i = 0; i < 8; i++)
#pragma unroll
            for (int j = 0; j < 4; j++) acc[i][j] = 0.0f;

        for (int c = 0; c < 4; c++) {
            const int k0 = c * 64;
            __syncthreads();
            float4 gw4 = *(const float4*)(gnw + g * VDIM + k0 + kq * 4);
            float4 gb4 = *(const float4*)(gnb + g * VDIM + k0 + kq * 4);
#pragma unroll
            for (int it = 0; it < 8; it++) {
                int tok = tb + 16 * it;
                float4 v = *(const float4*)(y + (size_t)(tok0 + tok) * DIMC + g * VDIM + k0 + kq * 4);
                float z0 = fmaf((v.x - mu) * rstd, gw4.x, gb4.x);
                float z1 = fmaf((v.y - mu) * rstd, gw4.y, gb4.y);
                float z2 = fmaf((v.z - mu) * rstd, gw4.z, gb4.z);
                float z3 = fmaf((v.w - mu) * rstd, gw4.w, gb4.w);
                As[kq * 4 + 0][tok] = z0; As[kq * 4 + 1][tok] = z1;
                As[kq * 4 + 2][tok] = z2; As[kq * 4 + 3][tok] = z3;
                if (vt == 0) zacc[it] += (double)z0 * z0 + (double)z1 * z1
                                       + (double)z2 * z2 + (double)z3 * z3;
            }
#pragma unroll
            for (int it = 0; it < 4; it++) {
                int v = tb + 16 * it;
                float4 ev = *(const float4*)(emb + (size_t)((v0 + v) * 2 + g) * VDIM + k0 + kq * 4);
                Es[kq * 4 + 0][v] = ev.x; Es[kq * 4 + 1][v] = ev.y;
                Es[kq * 4 + 2][v] = ev.z; Es[kq * 4 + 3][v] = ev.w;
            }
            __syncthreads();
#pragma unroll 8
            for (int k = 0; k < 64; k++) {
                const float4 a0 = *(const float4*)&As[k][ty * 8];
                const float4 a1 = *(const float4*)&As[k][ty * 8 + 4];
                const float4 e4 = *(const float4*)&Es[k][tx * 4];
                float av[8] = {a0.x, a0.y, a0.z, a0.w, a1.x, a1.y, a1.z, a1.w};
                float ev[4] = {e4.x, e4.y, e4.z, e4.w};
#pragma unroll
                for (int i = 0; i < 8; i++)
#pragma unroll
                    for (int j = 0; j < 4; j++) acc[i][j] = fmaf(av[i], ev[j], acc[i][j]);
            }
        }
        if (vt == 0) {
            // per-token z_sq: fp64 partials -> LDS -> correctly-rounded f32
#pragma unroll
            for (int it = 0; it < 8; it++) zpartd[tid + 256 * it] = zacc[it];
            __syncthreads();
            if (tid < 128) {
                double s = 0.0;
                for (int q = 0; q < 16; q++) s += zpartd[tid * 16 + q];
                zsq[tid] = (float)s;
            }
            __syncthreads();
#pragma unroll
            for (int i = 0; i < 8; i++) zs[i] = zsq[ty * 8 + i];
        }
        // argmin over quantized d2 = fl(fl(z_sq - 2*dot) + e_sq); ties -> lowest v
        float esql[4];
#pragma unroll
        for (int j = 0; j < 4; j++) esql[j] = ws[OFF_ESQ + (size_t)(v0 + tx * 4 + j) * 2 + g];
#pragma unroll
        for (int i = 0; i < 8; i++)
#pragma unroll
            for (int j = 0; j < 4; j++) {
                float t = zs[i] - 2.0f * acc[i][j];   // fma(-2,acc,zs): identical (2*dot exact)
                float d2 = t + esql[j];
                int v = v0 + tx * 4 + j;
                if (d2 < best_r[i]) { best_r[i] = d2; best_v[i] = v; }
            }
    }
    __syncthreads();   // zpartd reads done; safe to reuse as red_r/red_v
#pragma unroll
    for (int i = 0; i < 8; i++) {
        red_r[(ty * 8 + i) * 16 + tx] = best_r[i];
        red_v[(ty * 8 + i) * 16 + tx] = best_v[i];
    }
    __syncthreads();
    if (tid < 128) {
        float br = red_r[tid * 16]; int bv = red_v[tid * 16];
        for (int s = 1; s < 16; s++) {
            float r = red_r[tid * 16 + s]; int v = red_v[tid * 16 + s];
            if (r < br || (r == br && v < bv)) { br = r; bv = v; }
        }
        idxs[tid] = bv;
        dl[tid] = br;   // d2min (includes z_sq)
        out[IDX_OFF + (size_t)(tok0 + tid) * 2 + g] = (float)bv;
        atomicAdd(&hist[g * 320 + bv], 1);
    }
    __syncthreads();
    for (int s = 64; s; s >>= 1) {
        if (tid < s) dl[tid] += dl[tid + s];
        __syncthreads();
    }
    if (tid == 0) atomicAdd(&ws[OFF_LOSS], dl[0]);
    // x_out = zq gather (all y reads for this block are complete)
#pragma unroll 4
    for (int it = 0; it < 32; it++) {
        int j = tid + 256 * it;
        int tok = j >> 6, dq = j & 63;
        float4 v = *(const float4*)(emb + (size_t)(idxs[tok] * 2 + g) * VDIM + dq * 4);
        *(float4*)(out + (size_t)(tok0 + tok) * DIMC + g * VDIM + dq * 4) = v;
    }
}

__global__ void k_final(float* out, float* ws) {
    __shared__ float red[512];
    int tid = threadIdx.x;
    int* hist = ((int*)ws) + OFF_HIST;
    float ppl = 0.0f;
    for (int g = 0; g < 2; g++) {
        float term = 0.0f;
        if (tid < 320) {
            float p = (float)hist[g * 320 + tid] * (1.0f / 32768.0f);
            term = p * logf(p + 1e-7f);
        }
        red[tid] = term;
        __syncthreads();
        for (int s = 256; s; s >>= 1) {
            if (tid < s) red[tid] += red[tid + s];
            __syncthreads();
        }
        if (tid == 0) ppl += expf(-red[0]);
        __syncthreads();
    }
    if (tid == 0) {
        out[PPL_OFF] = ppl;
        out[KM_OFF] = 1.25f * ws[OFF_LOSS] / 16777216.0f;
    }
}

extern "C" void kernel_launch(void* const* d_in, const int* in_sizes, int n_in,
                              void* d_out, int out_size, void* d_ws, size_t ws_size,
                              hipStream_t stream) {
    (void)in_sizes; (void)n_in; (void)out_size; (void)ws_size;
    const float* x      = (const float*)d_in[0];
    const float* conv_w = (const float*)d_in[1];
    const float* gn_w   = (const float*)d_in[2];
    const float* gn_b   = (const float*)d_in[3];
    const float* emb    = (const float*)d_in[4];
    float* out = (float*)d_out;
    float* ws  = (float*)d_ws;

    hipLaunchKernelGGL(k_init,  dim3(7),         dim3(256), 0, stream, ws);
    hipLaunchKernelGGL(k_esq,   dim3(160),       dim3(256), 0, stream, emb, ws);
    hipLaunchKernelGGL(k_gemm,  dim3(256, 4, 2), dim3(256), 0, stream, x, conv_w, out, ws);
    hipLaunchKernelGGL(k_stats, dim3(1),         dim3(64),  0, stream, ws);
    hipLaunchKernelGGL(k_vq,    dim3(256, 2),    dim3(256), 0, stream, emb, gn_w, gn_b, out, ws);
    hipLaunchKernelGGL(k_final, dim3(1),         dim3(512), 0, stream, out, ws);
}